// Round 14
// baseline (558.565 us; speedup 1.0000x reference)
//
#include <hip/hip_runtime.h>

// DGMC top-k correspondence, MI355X — bf16 MFMA candidate GEMM + f64 refine.
// Phase 0: convert h_t fp32 -> bf16, granule-swizzled (phys g holds logical g^(row&31)).
// Phase 1: S^T tiles via mfma_f32_32x32x16_bf16 (A=h_t from LDS, B=h_s in regs).
//          Per-lane top-10 as SORTED PACKED uints: key = bits(S+256.f) & VMASK | (rd<<4|r).
//          SKEWED PIPELINE: dual acc (A/B); body(rd) = stage(rd+1) || chain(tile rd,
//          into NEW) with pack(OLD = tile rd-1) interleaved || extract-scan of OLD in
//          the chain's latency shadow. (r13 bug: LDS buffer-1 offset was written as
//          16384 SHORTS — a byte offset in short units — staging odd tiles 16 KB out
//          of bounds; garbage odd tiles -> eidx absmax 9981. Stride is 8192 shorts.)
//          launch_bounds(256,3): kernel carries a 64-reg persistent B-panel; the
//          (256,4) 128-reg cap spilled THREE times (r5/r6/r11) — 3 blocks/CU stable.
//          Pt=14 (r9: bigger Pt replicates the B-panel prologue, +60 MB fetch).
//          PS=736 -> rdbits=5 -> 23 value bits (quantum 2^-6; r8's 0.5 quantum
//          dropped true top-10 members -> idx fail).
// Phase 2: per-row merge of packed chains -> top-12 (key,t) by payload ripple-insert.
// Phase 3: f64 re-eval, one block/row, coalesced 256B-per-instruction gathers,
//          lane-parallel rank, softmax, scatter write.

typedef __attribute__((ext_vector_type(8)))  short bf16x8;
typedef __attribute__((ext_vector_type(16))) float f32x16;
typedef __attribute__((ext_vector_type(8)))  unsigned short u16x8;

#define K_TOP 10
#define CAND_M 12
#define CDIM 256
#define LDS_HALF 8192   // shorts per 32x256 tile buffer (16 KB)

#define GLD_LDS(src, dst) \
    __builtin_amdgcn_global_load_lds((const __attribute__((address_space(1))) void*)(src), \
                                     (__attribute__((address_space(3))) void*)(dst), 16, 0, 0)

__device__ __forceinline__ unsigned short f2bf(float f) {
    unsigned u = __float_as_uint(f);
    u += 0x7fffu + ((u >> 16) & 1u);      // RNE
    return (unsigned short)(u >> 16);
}

__device__ __forceinline__ unsigned umax2(unsigned a, unsigned b) { return a > b ? a : b; }
__device__ __forceinline__ unsigned umax3(unsigned a, unsigned b, unsigned c) {
    return umax2(umax2(a, b), c);          // fuses to v_max3_u32
}

__device__ __forceinline__ unsigned umax16(const unsigned (&p)[16]) {
    unsigned x0 = umax3(p[0],  p[1],  p[2]);
    unsigned x1 = umax3(p[3],  p[4],  p[5]);
    unsigned x2 = umax3(p[6],  p[7],  p[8]);
    unsigned x3 = umax3(p[9],  p[10], p[11]);
    unsigned x4 = umax3(p[12], p[13], p[14]);
    return umax2(umax3(x0, x1, x2), umax3(x3, x4, p[15]));
}

// Branchless ripple-insert of v into descending-sorted tv. No-op when v <= tv[K-1].
template <int K>
__device__ __forceinline__ void sorted_insert(unsigned (&tv)[K], unsigned v) {
    bool m[K];
#pragma unroll
    for (int q = 0; q < K; ++q) m[q] = tv[q] >= v;
    unsigned nv[K];
    nv[0] = m[0] ? tv[0] : v;
#pragma unroll
    for (int q = 1; q < K; ++q)
        nv[q] = m[q] ? tv[q] : (m[q - 1] ? v : tv[q - 1]);
#pragma unroll
    for (int q = 0; q < K; ++q) tv[q] = nv[q];
}

// Payload-carrying variant: key array + t array stay in registers (full unroll).
__device__ __forceinline__ void sorted_insert2(unsigned (&tk)[CAND_M], int (&tt)[CAND_M],
                                               unsigned k, int t) {
    bool m[CAND_M];
#pragma unroll
    for (int q = 0; q < CAND_M; ++q) m[q] = tk[q] >= k;
    unsigned nk[CAND_M]; int nt[CAND_M];
    nk[0] = m[0] ? tk[0] : k;
    nt[0] = m[0] ? tt[0] : t;
#pragma unroll
    for (int q = 1; q < CAND_M; ++q) {
        nk[q] = m[q] ? tk[q] : (m[q - 1] ? k : tk[q - 1]);
        nt[q] = m[q] ? tt[q] : (m[q - 1] ? t : tt[q - 1]);
    }
#pragma unroll
    for (int q = 0; q < CAND_M; ++q) { tk[q] = nk[q]; tt[q] = nt[q]; }
}

// ---------- Phase 0: fp32 -> bf16 with per-row granule XOR swizzle ----------
__global__ void conv_swz(const float* __restrict__ in, unsigned short* __restrict__ out, int N)
{
    int gid = blockIdx.x * blockDim.x + threadIdx.x;
    int row = gid >> 5, gl = gid & 31;
    if (row >= N) return;
    const float4* src = (const float4*)(in + (size_t)row * CDIM + gl * 8);
    float4 a0 = src[0], a1 = src[1];
    u16x8 o;
    o[0] = f2bf(a0.x); o[1] = f2bf(a0.y); o[2] = f2bf(a0.z); o[3] = f2bf(a0.w);
    o[4] = f2bf(a1.x); o[5] = f2bf(a1.y); o[6] = f2bf(a1.z); o[7] = f2bf(a1.w);
    *(u16x8*)(out + (size_t)row * CDIM + ((gl ^ (row & 31)) * 8)) = o;
}

// ---------- Phase 1: MFMA GEMM + per-lane packed top-10 ----------
__device__ __forceinline__ void stage32(const unsigned short* __restrict__ htb,
                                        short* ldsbuf, int tbase, int Nt,
                                        int tid, int wbase) {
#pragma unroll
    for (int it = 0; it < 4; ++it) {
        int pp = it * 256 + tid;
        int rr = pp >> 5, gg = pp & 31;
        int grow = tbase + rr; grow = grow < Nt ? grow : Nt - 1;
        GLD_LDS(htb + (size_t)grow * CDIM + gg * 8, ldsbuf + (it * 256 + wbase) * 8);
    }
}

// block = 256 thr = 4 waves; wave w owns 32 s-cols (block spans 128 s).
// LDS: 2 x (32 t-rows x 256 bf16) = 32 KB double buffer (stride LDS_HALF shorts).
__global__ __launch_bounds__(256, 3) void topk_mfma(
    const float* __restrict__ ehs, const float* __restrict__ rhs_,
    const unsigned short* __restrict__ ehtb, const unsigned short* __restrict__ rhtb,
    unsigned* __restrict__ partials, int Ns, int Nt, int Pt, int SB, int PS,
    unsigned VMASK)
{
    __shared__ short ldsT[2 * LDS_HALF];

    const int tid = threadIdx.x;
    const int w = tid >> 6, lane = tid & 63;
    const int l5 = lane & 31, hi = lane >> 5;
    const int wbase = tid & ~63;
    const int CH = 2 * Pt;

    const int bid  = blockIdx.x;
    const int prob = bid / (Pt * SB);
    const int rem  = bid % (Pt * SB);
    const int p    = rem / SB, sb = rem % SB;

    const float* hs = prob ? rhs_ : ehs;
    const unsigned short* htb = prob ? rhtb : ehtb;

    const int srow = sb * 128 + w * 32 + l5;
    const int srd  = srow < Ns ? srow : Ns - 1;

    // B-panel: h_s[srd][kk*16 + hi*8 + j], j=0..7 -> 16 frags (64 regs), persistent.
    bf16x8 b[16];
#pragma unroll
    for (int kk = 0; kk < 16; ++kk) {
        const float4* sp = (const float4*)(hs + (size_t)srd * CDIM + kk * 16 + hi * 8);
        float4 f0 = sp[0], f1 = sp[1];
        bf16x8 t;
        t[0] = (short)f2bf(f0.x); t[1] = (short)f2bf(f0.y);
        t[2] = (short)f2bf(f0.z); t[3] = (short)f2bf(f0.w);
        t[4] = (short)f2bf(f1.x); t[5] = (short)f2bf(f1.y);
        t[6] = (short)f2bf(f1.z); t[7] = (short)f2bf(f1.w);
        b[kk] = t;
    }

    const int t0 = p * PS;
    const int t1 = min(t0 + PS, Nt);

    unsigned tvp[K_TOP];
#pragma unroll
    for (int q = 0; q < K_TOP; ++q) tvp[q] = 0u;

    const int rounds = (t1 > t0) ? ((t1 - t0 + 31) >> 5) : 0;

    if (rounds > 0) {
        // prologue: tile0 staged+computed; tile1 stage overlaps the tile0 chain
        stage32(htb, ldsT, t0, Nt, tid, wbase);
        __syncthreads();
        if (rounds > 1)
            stage32(htb, ldsT + LDS_HALF, t0 + 32, Nt, tid, wbase);

        f32x16 accA, accB;
        {
            const short* rowp = ldsT + l5 * CDIM;
#pragma unroll
            for (int r = 0; r < 16; ++r) accA[r] = 256.0f;
#pragma unroll
            for (int kk = 0; kk < 16; ++kk) {
                bf16x8 a = *(const bf16x8*)(rowp + (((kk * 2 + hi) ^ l5) * 8));
                accA = __builtin_amdgcn_mfma_f32_32x32x16_bf16(a, b[kk], accA, 0, 0, 0);
            }
        }
        __syncthreads();   // tile1 ready; tile0 LDS reads drained

        // body(OLD, NEW, RD): stage RD+1 | chain tile RD -> NEW, pack OLD interleaved
        // | scan OLD's pu in the chain's latency shadow | barrier.
        // All tiles scanned here (0..rounds-2) are FULL -> no guard needed.
#define BODY(OLD, NEW, RD) {                                                      \
            if ((RD) + 1 < rounds)                                                \
                stage32(htb, ldsT + (((RD) + 1) & 1) * LDS_HALF,                  \
                        t0 + ((RD) + 1) * 32, Nt, tid, wbase);                    \
            const short* rowp_ = ldsT + ((RD) & 1) * LDS_HALF + l5 * CDIM;        \
            const unsigned ibase_ = (unsigned)(((RD) - 1) << 4);                  \
            unsigned pu[16];                                                      \
            _Pragma("unroll")                                                     \
            for (int r = 0; r < 16; ++r) NEW[r] = 256.0f;                         \
            _Pragma("unroll")                                                     \
            for (int kk = 0; kk < 16; ++kk) {                                     \
                bf16x8 a = *(const bf16x8*)(rowp_ + (((kk * 2 + hi) ^ l5) * 8));  \
                NEW = __builtin_amdgcn_mfma_f32_32x32x16_bf16(a, b[kk], NEW,      \
                                                              0, 0, 0);           \
                pu[kk] = (__float_as_uint(OLD[kk]) & VMASK)                       \
                         | (ibase_ + (unsigned)kk);                               \
            }                                                                     \
            unsigned mx = umax16(pu);                                             \
            while (__any((int)(mx > tvp[K_TOP - 1]))) {                           \
                sorted_insert<K_TOP>(tvp, mx);                                    \
                _Pragma("unroll")                                                 \
                for (int r = 0; r < 16; ++r) pu[r] = (pu[r] == mx) ? 0u : pu[r];  \
                mx = umax16(pu);                                                  \
            }                                                                     \
            __syncthreads();                                                      \
        }

        int rd = 1;
        for (; rd + 1 < rounds; rd += 2) {
            BODY(accA, accB, rd);
            BODY(accB, accA, (rd + 1));
        }
        bool lastInB = false;
        if (rd < rounds) { BODY(accA, accB, rd); lastInB = true; }
#undef BODY

        // epilogue: scan the final tile (rounds-1), the only one that can be partial
        {
            const int rdl = rounds - 1;
            const int tb  = t0 + rdl * 32;
            const unsigned ibase = (unsigned)(rdl << 4);
            unsigned pu[16];
#pragma unroll
            for (int r = 0; r < 16; ++r) {
                float v = lastInB ? accB[r] : accA[r];
                pu[r] = (__float_as_uint(v) & VMASK) | (ibase + (unsigned)r);
            }
            if (tb + 32 > t1) {
#pragma unroll
                for (int r = 0; r < 16; ++r) {
                    int t = tb + 4 * hi + (r & 3) + 8 * (r >> 2);
                    if (t >= t1) pu[r] = 0u;
                }
            }
            unsigned mx = umax16(pu);
            while (__any((int)(mx > tvp[K_TOP - 1]))) {
                sorted_insert<K_TOP>(tvp, mx);
#pragma unroll
                for (int r = 0; r < 16; ++r)
                    pu[r] = (pu[r] == mx) ? 0u : pu[r];
                mx = umax16(pu);
            }
        }
    }

    // chain write: RAW keys, layout [prob][chain][q][Ns], coalesced across srow
    if (srow < Ns) {
        unsigned* wp = partials + ((size_t)(prob * CH + (p * 2 + hi)) * K_TOP) * Ns + srow;
#pragma unroll
        for (int q = 0; q < K_TOP; ++q) wp[(size_t)q * Ns] = tvp[q];
    }
}

// ---------- Phase 2: merge packed chains -> top-12 candidate t's ----------
__global__ void topk_mergecand(const unsigned* __restrict__ partials, int* __restrict__ cand,
                               int Ns, int CH, int PS, unsigned rdMask)
{
    int g = blockIdx.x * blockDim.x + threadIdx.x;
    if (g >= 2 * Ns) return;
    const int prob = g >= Ns ? 1 : 0;
    const int row  = g - prob * Ns;
    const unsigned* src = partials + ((size_t)prob * CH * K_TOP) * Ns + row;

    unsigned tvk[CAND_M]; int tvt[CAND_M];
#pragma unroll
    for (int q = 0; q < CAND_M; ++q) { tvk[q] = 0u; tvt[q] = 0; }

    for (int c = 0; c < CH; ++c) {
        const int tbase = (c >> 1) * PS + 4 * (c & 1);
#pragma unroll
        for (int q = 0; q < K_TOP; ++q) {
            unsigned k = src[(size_t)(c * K_TOP + q) * Ns];
            if (k > tvk[CAND_M - 1]) {
                unsigned rd = (k >> 4) & rdMask;
                unsigned r  = k & 15u;
                int t = tbase + (int)rd * 32 + (int)((r & 3) + 8 * (r >> 2));
                sorted_insert2(tvk, tvt, k, t);
            }
        }
    }
    int* dst = cand + (size_t)g * CAND_M;
#pragma unroll
    for (int q = 0; q < CAND_M; ++q) dst[q] = tvt[q];
}

// ---------- Phase 3: f64 refine, coalesced, one block per row ----------
// tid = m*16 + c: candidate m (0..15, active m<CAND_M), chunk c (0..15). Lane c
// reads float4 granules {c, c+16, c+32, c+48} -> each load instruction covers a
// contiguous 256 B of one row. f64 accumulate, shfl reduce over c, LDS rank+softmax.
__global__ __launch_bounds__(256) void topk_refine(
    const float* __restrict__ ehs, const float* __restrict__ eht,
    const float* __restrict__ rhs_, const float* __restrict__ rht,
    const int* __restrict__ cand, float* __restrict__ out, int Ns)
{
    __shared__ double svd[CAND_M];
    __shared__ int    sci[CAND_M];

    const int wid = blockIdx.x;               // one row per block, grid = 2*Ns
    const int tid = threadIdx.x;
    const int m = tid >> 4, c = tid & 15;

    const int prob = wid < Ns ? 0 : 1;
    const int row  = prob ? (wid - Ns) : wid;
    const float* hs = prob ? rhs_ : ehs;
    const float* ht = prob ? rht  : eht;

    if (m < CAND_M) {
        const int t = cand[(size_t)wid * CAND_M + m];
        const float4* ap = (const float4*)(hs + (size_t)row * CDIM);
        const float4* bp = (const float4*)(ht + (size_t)t   * CDIM);

        double s = 0.0;
#pragma unroll
        for (int i = 0; i < 4; ++i) {
            float4 av = ap[c + 16 * i];
            float4 bv = bp[c + 16 * i];
            s += (double)av.x * (double)bv.x + (double)av.y * (double)bv.y
               + (double)av.z * (double)bv.z + (double)av.w * (double)bv.w;
        }
        // 16-lane group (same m, c = low 4 bits): butterfly over c
        s += __shfl_xor(s, 1, 64);
        s += __shfl_xor(s, 2, 64);
        s += __shfl_xor(s, 4, 64);
        s += __shfl_xor(s, 8, 64);
        if (c == 0) { svd[m] = s; sci[m] = t; }
    }
    __syncthreads();

    if (tid < 16) {                           // all 16 lanes run the butterfly
        const bool act = tid < CAND_M;
        const double sm = act ? svd[tid] : -1.0e300;
        const int    tm = act ? sci[tid] : 0x7FFFFFFF;
        int rank = 0; double vmax = -1.0e300;
#pragma unroll
        for (int j = 0; j < CAND_M; ++j) {
            double vj = svd[j]; int cj = sci[j];
            bool better = (vj > sm) || (vj == sm && cj < tm);
            rank += better ? 1 : 0;
            vmax = fmax(vmax, vj);
        }
        float ex = (act && rank < K_TOP) ? __expf((float)(sm - vmax)) : 0.f;
        float ssum = ex;
        ssum += __shfl_xor(ssum, 1, 64);
        ssum += __shfl_xor(ssum, 2, 64);
        ssum += __shfl_xor(ssum, 4, 64);
        ssum += __shfl_xor(ssum, 8, 64);      // sum over the 16 lanes (inactive = 0)
        if (act && rank < K_TOP) {
            size_t nsk = (size_t)Ns * K_TOP;
            size_t so  = (size_t)wid * K_TOP;
            out[so + rank] = ex / ssum;
            out[2 * nsk + so + rank] = (float)tm;
        }
    }
}

extern "C" void kernel_launch(void* const* d_in, const int* in_sizes, int n_in,
                              void* d_out, int out_size, void* d_ws, size_t ws_size,
                              hipStream_t stream) {
    (void)n_in; (void)out_size;
    const float* eh_s = (const float*)d_in[0];
    const float* eh_t = (const float*)d_in[1];
    const float* rh_s = (const float*)d_in[2];
    const float* rh_t = (const float*)d_in[3];
    // d_in[4] is k (=10), compile-time constant here.

    const int Ns = in_sizes[0] / CDIM;
    const int Nt = in_sizes[1] / CDIM;
    const int SB = (Ns + 127) / 128;

    const size_t htbElems = (size_t)Nt * CDIM;          // per array, ushorts
    const size_t htbBytes = 2 * htbElems * 2;
    const size_t candBytes = (size_t)2 * Ns * CAND_M * sizeof(int);

    // Pt=14: 2212 blocks. r9 showed larger Pt replicates the B-panel prologue
    // (+60 MB fetch, +15 us). PS=736 -> up to 23 rounds.
    int Pt = 14;
    while (Pt > 1 &&
           htbBytes + (size_t)2 * Ns * (2 * Pt) * K_TOP * sizeof(unsigned) + candBytes > ws_size)
        Pt -= 1;
    const int PS = (int)((((size_t)Nt + Pt - 1) / Pt + 31) & ~(size_t)31);

    // idx-field width: 4 (r) + rdbits, where 2^rdbits >= PS/32. VMASK keeps the rest.
    int rdbits = 0;
    while ((1 << rdbits) < (PS >> 5)) ++rdbits;
    const int IDXB = 4 + rdbits;
    const unsigned VMASK  = ~((1u << IDXB) - 1u);
    const unsigned rdMask = (1u << rdbits) - 1u;

    unsigned short* htb_e = (unsigned short*)d_ws;
    unsigned short* htb_r = htb_e + htbElems;
    unsigned* partials = (unsigned*)(htb_r + htbElems);
    int*  cand = (int*)((char*)partials + (size_t)2 * Ns * (2 * Pt) * K_TOP * sizeof(unsigned));

    dim3 block(256);

    // Phase 0: convert both h_t arrays (swizzled bf16)
    int convBlocks = (Nt * 32 + 255) / 256;
    conv_swz<<<dim3(convBlocks), block, 0, stream>>>(eh_t, htb_e, Nt);
    conv_swz<<<dim3(convBlocks), block, 0, stream>>>(rh_t, htb_r, Nt);

    // Phase 1: MFMA GEMM + packed top-10 chains (skewed pipeline)
    topk_mfma<<<dim3(2 * Pt * SB), block, 0, stream>>>(eh_s, rh_s, htb_e, htb_r,
                                                       partials, Ns, Nt, Pt, SB, PS,
                                                       VMASK);

    // Phase 2: merge -> candidate t's (decode from chain id + packed rd,r)
    int nrows = 2 * Ns;
    topk_mergecand<<<dim3((nrows + 255) / 256), block, 0, stream>>>(partials, cand,
                                                                    Ns, 2 * Pt, PS, rdMask);

    // Phase 3: f64 refine + softmax + write (one block per row)
    topk_refine<<<dim3(nrows), block, 0, stream>>>(eh_s, eh_t, rh_s, rh_t,
                                                   cand, (float*)d_out, Ns);
}

// Round 15
// 327.971 us; speedup vs baseline: 1.7031x; 1.7031x over previous
//
#include <hip/hip_runtime.h>

// DGMC top-k correspondence, MI355X — bf16 MFMA candidate GEMM + f64 refine.
// FINAL FORM = r12 (best measured: 331.8 us) + fused conv dispatch.
// Phase 0: convert BOTH h_t arrays fp32 -> bf16 in one dispatch, granule-swizzled.
// Phase 1: S^T tiles via mfma_f32_32x32x16_bf16 (A=h_t from LDS, B=h_s in regs).
//          Per-lane top-10 as SORTED PACKED uints: key = bits(S+256.f) & VMASK | (rd<<4|r).
//          +256 bias folded into the MFMA C-init; SINGLE 16-MFMA acc chain.
//          launch_bounds(256,3): kernel carries a 64-reg persistent B-panel.
//          CLOSED LEVERS (counter-proven): (a) occupancy >3 blocks/CU — the
//          (256,4)/(256,5) caps spilled (r5: 785 MB, r6: 55 MB, r11: 119 MB scratch);
//          (b) dual-acc skewed pipeline — allocator spills the live-across-chain
//          state regardless of cap (r14: +465 MB fetch, VALUBusy 34%); (c) op-count
//          cuts — near-flat (r10/r12: -40 VALU/round = -3 us). r12's point is the
//          practical floor: MFMA floor 44 us (19%) + scan VALU + issue residue.
//          Pt=14 (r9: bigger Pt replicates the B-panel prologue, +60 MB fetch).
//          PS=736 -> rdbits=5 -> 23 value bits (quantum 2^-6; r8's 0.5 quantum
//          dropped true top-10 members -> idx fail).
// Phase 2: per-row merge of packed chains -> top-12 (key,t) by payload ripple-insert.
// Phase 3: f64 re-eval, one block/row, coalesced 256B-per-instruction gathers,
//          lane-parallel rank, softmax, scatter write.

typedef __attribute__((ext_vector_type(8)))  short bf16x8;
typedef __attribute__((ext_vector_type(16))) float f32x16;
typedef __attribute__((ext_vector_type(8)))  unsigned short u16x8;

#define K_TOP 10
#define CAND_M 12
#define CDIM 256

#define GLD_LDS(src, dst) \
    __builtin_amdgcn_global_load_lds((const __attribute__((address_space(1))) void*)(src), \
                                     (__attribute__((address_space(3))) void*)(dst), 16, 0, 0)

__device__ __forceinline__ unsigned short f2bf(float f) {
    unsigned u = __float_as_uint(f);
    u += 0x7fffu + ((u >> 16) & 1u);      // RNE
    return (unsigned short)(u >> 16);
}

__device__ __forceinline__ unsigned umax2(unsigned a, unsigned b) { return a > b ? a : b; }
__device__ __forceinline__ unsigned umax3(unsigned a, unsigned b, unsigned c) {
    return umax2(umax2(a, b), c);          // fuses to v_max3_u32
}

__device__ __forceinline__ unsigned umax16(const unsigned (&p)[16]) {
    unsigned x0 = umax3(p[0],  p[1],  p[2]);
    unsigned x1 = umax3(p[3],  p[4],  p[5]);
    unsigned x2 = umax3(p[6],  p[7],  p[8]);
    unsigned x3 = umax3(p[9],  p[10], p[11]);
    unsigned x4 = umax3(p[12], p[13], p[14]);
    return umax2(umax3(x0, x1, x2), umax3(x3, x4, p[15]));
}

// Branchless ripple-insert of v into descending-sorted tv. No-op when v <= tv[K-1].
template <int K>
__device__ __forceinline__ void sorted_insert(unsigned (&tv)[K], unsigned v) {
    bool m[K];
#pragma unroll
    for (int q = 0; q < K; ++q) m[q] = tv[q] >= v;
    unsigned nv[K];
    nv[0] = m[0] ? tv[0] : v;
#pragma unroll
    for (int q = 1; q < K; ++q)
        nv[q] = m[q] ? tv[q] : (m[q - 1] ? v : tv[q - 1]);
#pragma unroll
    for (int q = 0; q < K; ++q) tv[q] = nv[q];
}

// Payload-carrying variant: key array + t array stay in registers (full unroll).
__device__ __forceinline__ void sorted_insert2(unsigned (&tk)[CAND_M], int (&tt)[CAND_M],
                                               unsigned k, int t) {
    bool m[CAND_M];
#pragma unroll
    for (int q = 0; q < CAND_M; ++q) m[q] = tk[q] >= k;
    unsigned nk[CAND_M]; int nt[CAND_M];
    nk[0] = m[0] ? tk[0] : k;
    nt[0] = m[0] ? tt[0] : t;
#pragma unroll
    for (int q = 1; q < CAND_M; ++q) {
        nk[q] = m[q] ? tk[q] : (m[q - 1] ? k : tk[q - 1]);
        nt[q] = m[q] ? tt[q] : (m[q - 1] ? t : tt[q - 1]);
    }
#pragma unroll
    for (int q = 0; q < CAND_M; ++q) { tk[q] = nk[q]; tt[q] = nt[q]; }
}

// ---------- Phase 0: fp32 -> bf16 with per-row granule XOR swizzle (both arrays) ----------
__global__ void conv_swz2(const float* __restrict__ inE, unsigned short* __restrict__ outE,
                          const float* __restrict__ inR, unsigned short* __restrict__ outR,
                          int N)
{
    int gid = blockIdx.x * blockDim.x + threadIdx.x;
    int half = N * 32;
    const float* in = (gid < half) ? inE : inR;
    unsigned short* out = (gid < half) ? outE : outR;
    int g2 = (gid < half) ? gid : gid - half;
    int row = g2 >> 5, gl = g2 & 31;
    if (row >= N) return;
    const float4* src = (const float4*)(in + (size_t)row * CDIM + gl * 8);
    float4 a0 = src[0], a1 = src[1];
    u16x8 o;
    o[0] = f2bf(a0.x); o[1] = f2bf(a0.y); o[2] = f2bf(a0.z); o[3] = f2bf(a0.w);
    o[4] = f2bf(a1.x); o[5] = f2bf(a1.y); o[6] = f2bf(a1.z); o[7] = f2bf(a1.w);
    *(u16x8*)(out + (size_t)row * CDIM + ((gl ^ (row & 31)) * 8)) = o;
}

// ---------- Phase 1: MFMA GEMM + per-lane packed top-10 ----------
__device__ __forceinline__ void stage32(const unsigned short* __restrict__ htb,
                                        short* ldsbuf, int tbase, int Nt,
                                        int tid, int wbase) {
#pragma unroll
    for (int it = 0; it < 4; ++it) {
        int pp = it * 256 + tid;
        int rr = pp >> 5, gg = pp & 31;
        int grow = tbase + rr; grow = grow < Nt ? grow : Nt - 1;
        GLD_LDS(htb + (size_t)grow * CDIM + gg * 8, ldsbuf + (it * 256 + wbase) * 8);
    }
}

// block = 256 thr = 4 waves; wave w owns 32 s-cols (block spans 128 s).
// LDS: 2 x (32 t-rows x 256 bf16) = 32 KB double buffer.
__global__ __launch_bounds__(256, 3) void topk_mfma(
    const float* __restrict__ ehs, const float* __restrict__ rhs_,
    const unsigned short* __restrict__ ehtb, const unsigned short* __restrict__ rhtb,
    unsigned* __restrict__ partials, int Ns, int Nt, int Pt, int SB, int PS,
    unsigned VMASK)
{
    __shared__ short ldsT[2 * 32 * 256];

    const int tid = threadIdx.x;
    const int w = tid >> 6, lane = tid & 63;
    const int l5 = lane & 31, hi = lane >> 5;
    const int wbase = tid & ~63;
    const int CH = 2 * Pt;

    const int bid  = blockIdx.x;
    const int prob = bid / (Pt * SB);
    const int rem  = bid % (Pt * SB);
    const int p    = rem / SB, sb = rem % SB;

    const float* hs = prob ? rhs_ : ehs;
    const unsigned short* htb = prob ? rhtb : ehtb;

    const int srow = sb * 128 + w * 32 + l5;
    const int srd  = srow < Ns ? srow : Ns - 1;

    // B-panel: h_s[srd][kk*16 + hi*8 + j], j=0..7 -> 16 frags (64 regs), persistent.
    bf16x8 b[16];
#pragma unroll
    for (int kk = 0; kk < 16; ++kk) {
        const float4* sp = (const float4*)(hs + (size_t)srd * CDIM + kk * 16 + hi * 8);
        float4 f0 = sp[0], f1 = sp[1];
        bf16x8 t;
        t[0] = (short)f2bf(f0.x); t[1] = (short)f2bf(f0.y);
        t[2] = (short)f2bf(f0.z); t[3] = (short)f2bf(f0.w);
        t[4] = (short)f2bf(f1.x); t[5] = (short)f2bf(f1.y);
        t[6] = (short)f2bf(f1.z); t[7] = (short)f2bf(f1.w);
        b[kk] = t;
    }

    const int t0 = p * PS;
    const int t1 = min(t0 + PS, Nt);

    unsigned tvp[K_TOP];
#pragma unroll
    for (int q = 0; q < K_TOP; ++q) tvp[q] = 0u;

    const int rounds = (t1 > t0) ? ((t1 - t0 + 31) >> 5) : 0;

    if (rounds > 0) {
        stage32(htb, ldsT, t0, Nt, tid, wbase);
        __syncthreads();

        for (int rd = 0; rd < rounds; ++rd) {
            const int cur = rd & 1;
            const int tb  = t0 + rd * 32;
            if (rd + 1 < rounds)
                stage32(htb, ldsT + (cur ^ 1) * 8192, tb + 32, Nt, tid, wbase);

            const bool guard = (tb + 32 > t1);
            const short* rowp = ldsT + cur * 8192 + l5 * CDIM;
            // single acc chain; +256 pack bias via C-init (free vs zero-init).
            f32x16 acc;
#pragma unroll
            for (int r = 0; r < 16; ++r) acc[r] = 256.0f;
#pragma unroll
            for (int kk = 0; kk < 16; ++kk) {
                bf16x8 a = *(const bf16x8*)(rowp + (((kk * 2 + hi) ^ l5) * 8));
                acc = __builtin_amdgcn_mfma_f32_32x32x16_bf16(a, b[kk], acc, 0, 0, 0);
            }
            // ---- packed scan: one s-col per lane, 16 t-values ----
            // biased S is a positive float -> uint order == value order.
            // idx = (rd<<4)|r in low bits; decode to t happens in the MERGE kernel.
            const unsigned ibase = (unsigned)(rd << 4);
            unsigned pu[16];
#pragma unroll
            for (int r = 0; r < 16; ++r)
                pu[r] = (__float_as_uint(acc[r]) & VMASK) | (ibase + (unsigned)r);
            if (guard) {
#pragma unroll
                for (int r = 0; r < 16; ++r) {
                    int t = tb + 4 * hi + (r & 3) + 8 * (r >> 2);
                    if (t >= t1) pu[r] = 0u;
                }
            }
            unsigned mx = umax16(pu);
            while (__any((int)(mx > tvp[K_TOP - 1]))) {
                sorted_insert<K_TOP>(tvp, mx);   // no-op for lanes with mx <= tvp[9]
#pragma unroll
                for (int r = 0; r < 16; ++r)
                    pu[r] = (pu[r] == mx) ? 0u : pu[r];
                mx = umax16(pu);
            }
            __syncthreads();
        }
    }

    // chain write: RAW keys, layout [prob][chain][q][Ns], coalesced across srow
    if (srow < Ns) {
        unsigned* wp = partials + ((size_t)(prob * CH + (p * 2 + hi)) * K_TOP) * Ns + srow;
#pragma unroll
        for (int q = 0; q < K_TOP; ++q) wp[(size_t)q * Ns] = tvp[q];
    }
}

// ---------- Phase 2: merge packed chains -> top-12 candidate t's ----------
__global__ void topk_mergecand(const unsigned* __restrict__ partials, int* __restrict__ cand,
                               int Ns, int CH, int PS, unsigned rdMask)
{
    int g = blockIdx.x * blockDim.x + threadIdx.x;
    if (g >= 2 * Ns) return;
    const int prob = g >= Ns ? 1 : 0;
    const int row  = g - prob * Ns;
    const unsigned* src = partials + ((size_t)prob * CH * K_TOP) * Ns + row;

    unsigned tvk[CAND_M]; int tvt[CAND_M];
#pragma unroll
    for (int q = 0; q < CAND_M; ++q) { tvk[q] = 0u; tvt[q] = 0; }

    for (int c = 0; c < CH; ++c) {
        const int tbase = (c >> 1) * PS + 4 * (c & 1);
#pragma unroll
        for (int q = 0; q < K_TOP; ++q) {
            unsigned k = src[(size_t)(c * K_TOP + q) * Ns];
            if (k > tvk[CAND_M - 1]) {
                unsigned rd = (k >> 4) & rdMask;
                unsigned r  = k & 15u;
                int t = tbase + (int)rd * 32 + (int)((r & 3) + 8 * (r >> 2));
                sorted_insert2(tvk, tvt, k, t);
            }
        }
    }
    int* dst = cand + (size_t)g * CAND_M;
#pragma unroll
    for (int q = 0; q < CAND_M; ++q) dst[q] = tvt[q];
}

// ---------- Phase 3: f64 refine, coalesced, one block per row ----------
// tid = m*16 + c: candidate m (0..15, active m<CAND_M), chunk c (0..15). Lane c
// reads float4 granules {c, c+16, c+32, c+48} -> each load instruction covers a
// contiguous 256 B of one row. f64 accumulate, shfl reduce over c, LDS rank+softmax.
__global__ __launch_bounds__(256) void topk_refine(
    const float* __restrict__ ehs, const float* __restrict__ eht,
    const float* __restrict__ rhs_, const float* __restrict__ rht,
    const int* __restrict__ cand, float* __restrict__ out, int Ns)
{
    __shared__ double svd[CAND_M];
    __shared__ int    sci[CAND_M];

    const int wid = blockIdx.x;               // one row per block, grid = 2*Ns
    const int tid = threadIdx.x;
    const int m = tid >> 4, c = tid & 15;

    const int prob = wid < Ns ? 0 : 1;
    const int row  = prob ? (wid - Ns) : wid;
    const float* hs = prob ? rhs_ : ehs;
    const float* ht = prob ? rht  : eht;

    if (m < CAND_M) {
        const int t = cand[(size_t)wid * CAND_M + m];
        const float4* ap = (const float4*)(hs + (size_t)row * CDIM);
        const float4* bp = (const float4*)(ht + (size_t)t   * CDIM);

        double s = 0.0;
#pragma unroll
        for (int i = 0; i < 4; ++i) {
            float4 av = ap[c + 16 * i];
            float4 bv = bp[c + 16 * i];
            s += (double)av.x * (double)bv.x + (double)av.y * (double)bv.y
               + (double)av.z * (double)bv.z + (double)av.w * (double)bv.w;
        }
        // 16-lane group (same m, c = low 4 bits): butterfly over c
        s += __shfl_xor(s, 1, 64);
        s += __shfl_xor(s, 2, 64);
        s += __shfl_xor(s, 4, 64);
        s += __shfl_xor(s, 8, 64);
        if (c == 0) { svd[m] = s; sci[m] = t; }
    }
    __syncthreads();

    if (tid < 16) {                           // all 16 lanes run the butterfly
        const bool act = tid < CAND_M;
        const double sm = act ? svd[tid] : -1.0e300;
        const int    tm = act ? sci[tid] : 0x7FFFFFFF;
        int rank = 0; double vmax = -1.0e300;
#pragma unroll
        for (int j = 0; j < CAND_M; ++j) {
            double vj = svd[j]; int cj = sci[j];
            bool better = (vj > sm) || (vj == sm && cj < tm);
            rank += better ? 1 : 0;
            vmax = fmax(vmax, vj);
        }
        float ex = (act && rank < K_TOP) ? __expf((float)(sm - vmax)) : 0.f;
        float ssum = ex;
        ssum += __shfl_xor(ssum, 1, 64);
        ssum += __shfl_xor(ssum, 2, 64);
        ssum += __shfl_xor(ssum, 4, 64);
        ssum += __shfl_xor(ssum, 8, 64);      // sum over the 16 lanes (inactive = 0)
        if (act && rank < K_TOP) {
            size_t nsk = (size_t)Ns * K_TOP;
            size_t so  = (size_t)wid * K_TOP;
            out[so + rank] = ex / ssum;
            out[2 * nsk + so + rank] = (float)tm;
        }
    }
}

extern "C" void kernel_launch(void* const* d_in, const int* in_sizes, int n_in,
                              void* d_out, int out_size, void* d_ws, size_t ws_size,
                              hipStream_t stream) {
    (void)n_in; (void)out_size;
    const float* eh_s = (const float*)d_in[0];
    const float* eh_t = (const float*)d_in[1];
    const float* rh_s = (const float*)d_in[2];
    const float* rh_t = (const float*)d_in[3];
    // d_in[4] is k (=10), compile-time constant here.

    const int Ns = in_sizes[0] / CDIM;
    const int Nt = in_sizes[1] / CDIM;
    const int SB = (Ns + 127) / 128;

    const size_t htbElems = (size_t)Nt * CDIM;          // per array, ushorts
    const size_t htbBytes = 2 * htbElems * 2;
    const size_t candBytes = (size_t)2 * Ns * CAND_M * sizeof(int);

    // Pt=14: 2212 blocks. r9 showed larger Pt replicates the B-panel prologue
    // (+60 MB fetch, +15 us). PS=736 -> up to 23 rounds.
    int Pt = 14;
    while (Pt > 1 &&
           htbBytes + (size_t)2 * Ns * (2 * Pt) * K_TOP * sizeof(unsigned) + candBytes > ws_size)
        Pt -= 1;
    const int PS = (int)((((size_t)Nt + Pt - 1) / Pt + 31) & ~(size_t)31);

    // idx-field width: 4 (r) + rdbits, where 2^rdbits >= PS/32. VMASK keeps the rest.
    int rdbits = 0;
    while ((1 << rdbits) < (PS >> 5)) ++rdbits;
    const int IDXB = 4 + rdbits;
    const unsigned VMASK  = ~((1u << IDXB) - 1u);
    const unsigned rdMask = (1u << rdbits) - 1u;

    unsigned short* htb_e = (unsigned short*)d_ws;
    unsigned short* htb_r = htb_e + htbElems;
    unsigned* partials = (unsigned*)(htb_r + htbElems);
    int*  cand = (int*)((char*)partials + (size_t)2 * Ns * (2 * Pt) * K_TOP * sizeof(unsigned));

    dim3 block(256);

    // Phase 0: convert both h_t arrays (swizzled bf16), one dispatch
    int convBlocks = (2 * Nt * 32 + 255) / 256;
    conv_swz2<<<dim3(convBlocks), block, 0, stream>>>(eh_t, htb_e, rh_t, htb_r, Nt);

    // Phase 1: MFMA GEMM + packed top-10 chains
    topk_mfma<<<dim3(2 * Pt * SB), block, 0, stream>>>(eh_s, rh_s, htb_e, htb_r,
                                                       partials, Ns, Nt, Pt, SB, PS,
                                                       VMASK);

    // Phase 2: merge -> candidate t's (decode from chain id + packed rd,r)
    int nrows = 2 * Ns;
    topk_mergecand<<<dim3((nrows + 255) / 256), block, 0, stream>>>(partials, cand,
                                                                    Ns, 2 * Pt, PS, rdMask);

    // Phase 3: f64 refine + softmax + write (one block per row)
    topk_refine<<<dim3(nrows), block, 0, stream>>>(eh_s, eh_t, rh_s, rh_t,
                                                   cand, (float*)d_out, Ns);
}